// Round 1
// baseline (201.135 us; speedup 1.0000x reference)
//
#include <hip/hip_runtime.h>
#include <hip/hip_bf16.h>

typedef __attribute__((ext_vector_type(8))) unsigned short u16x8;
typedef __attribute__((ext_vector_type(8))) __bf16        bf16x8;
typedef __attribute__((ext_vector_type(4))) float         f32x4;

static constexpr int B_ = 8192;
static constexpr int I_ = 512;
static constexpr int H_ = 1024;
static constexpr int K_ = 1536;   // I_ + H_

__device__ __forceinline__ unsigned short f2bf(float f) {
    unsigned int u = __float_as_uint(f);
    u += 0x7FFF + ((u >> 16) & 1);          // round-to-nearest-even
    return (unsigned short)(u >> 16);
}

// fp32 -> bf16 convert, 8 elems/thread, vectorized
__global__ void cvt_bf16_kernel(const float* __restrict__ src,
                                unsigned short* __restrict__ dst, int n8) {
    int i = blockIdx.x * blockDim.x + threadIdx.x;
    if (i >= n8) return;
    const float4* s = (const float4*)src + (size_t)i * 2;
    float4 a = s[0], b = s[1];
    u16x8 o;
    o[0] = f2bf(a.x); o[1] = f2bf(a.y); o[2] = f2bf(a.z); o[3] = f2bf(a.w);
    o[4] = f2bf(b.x); o[5] = f2bf(b.y); o[6] = f2bf(b.z); o[7] = f2bf(b.w);
    *((u16x8*)dst + i) = o;
}

// C[m][n] = sum_k A[m][k] * W[n][k]  (both operands K-major, bf16, fp32 accum)
// A is split in K: k < I_ from Ax (stride I_), k >= I_ from Ah (stride H_).
// MODE 0: outf = 1/(softplus(z+b)+eps)           (inv_tau)
// MODE 1: outb = bf16(sigmoid(z+b) * hidden)     (gated)
// MODE 2: outf = hidden + (tanh(z+b)-hidden)*invtau
template<int MODE>
__global__ __launch_bounds__(256)
void gemm_ltc(const unsigned short* __restrict__ Ax,
              const unsigned short* __restrict__ Ah,
              const unsigned short* __restrict__ Wb,
              const float* __restrict__ bias,
              const float* __restrict__ hidden,
              const float* __restrict__ invtau,
              float* __restrict__ outf,
              unsigned short* __restrict__ outb)
{
    __shared__ __align__(16) unsigned short As[128 * 32];
    __shared__ __align__(16) unsigned short Bs[128 * 32];

    const int tid = threadIdx.x;
    const int w   = tid >> 6;       // wave 0..3
    const int l   = tid & 63;       // lane
    const int wr  = w >> 1;         // wave row 0..1
    const int wc  = w & 1;          // wave col 0..1
    const int m0  = blockIdx.y * 128;
    const int n0  = blockIdx.x * 128;

    f32x4 acc[4][4];
    #pragma unroll
    for (int i = 0; i < 4; i++)
        #pragma unroll
        for (int j = 0; j < 4; j++)
            acc[i][j] = (f32x4)0.0f;

    const int lr = l >> 2;          // 0..15: row within a 16-row stripe
    const int lk = (l & 3) * 8;     // k element offset for staging

    for (int kt = 0; kt < K_ / 32; ++kt) {
        const int k0 = kt * 32;
        const unsigned short* Abase;
        int rs, kc;
        if (k0 < I_) { Abase = Ax; rs = I_; kc = k0; }
        else         { Abase = Ah; rs = H_; kc = k0 - I_; }

        // stage A tile: 128 rows x 32 k (bf16), linear LDS, wave-uniform base
        #pragma unroll
        for (int it = 0; it < 2; ++it) {
            const int rr = it * 64 + w * 16;
            const unsigned short* g = Abase + (size_t)(m0 + rr + lr) * rs + kc + lk;
            __builtin_amdgcn_global_load_lds(
                (const __attribute__((address_space(1))) void*)g,
                (__attribute__((address_space(3))) void*)(As + rr * 32),
                16, 0, 0);
        }
        // stage B tile: W rows n0..n0+127, same k slice
        #pragma unroll
        for (int it = 0; it < 2; ++it) {
            const int rr = it * 64 + w * 16;
            const unsigned short* g = Wb + (size_t)(n0 + rr + lr) * K_ + k0 + lk;
            __builtin_amdgcn_global_load_lds(
                (const __attribute__((address_space(1))) void*)g,
                (__attribute__((address_space(3))) void*)(Bs + rr * 32),
                16, 0, 0);
        }
        __syncthreads();   // compiler drains vmcnt(0) before barrier

        const int fr = l & 15;
        const int ks = (l >> 4) * 8;
        bf16x8 a[4], b[4];
        #pragma unroll
        for (int mi = 0; mi < 4; mi++)
            a[mi] = *(const bf16x8*)(As + (wr * 64 + mi * 16 + fr) * 32 + ks);
        #pragma unroll
        for (int ni = 0; ni < 4; ni++)
            b[ni] = *(const bf16x8*)(Bs + (wc * 64 + ni * 16 + fr) * 32 + ks);
        #pragma unroll
        for (int mi = 0; mi < 4; mi++)
            #pragma unroll
            for (int ni = 0; ni < 4; ni++)
                acc[mi][ni] = __builtin_amdgcn_mfma_f32_16x16x32_bf16(
                    a[mi], b[ni], acc[mi][ni], 0, 0, 0);
        __syncthreads();   // protect LDS before next stage
    }

    // epilogue: C/D layout col = lane&15, row = (lane>>4)*4 + j
    const int fr   = l & 15;
    const int rsub = (l >> 4) * 4;
    #pragma unroll
    for (int mi = 0; mi < 4; mi++) {
        #pragma unroll
        for (int ni = 0; ni < 4; ni++) {
            const int gn = n0 + wc * 64 + ni * 16 + fr;
            const float bv = bias[gn];
            #pragma unroll
            for (int j = 0; j < 4; j++) {
                const int gm = m0 + wr * 64 + mi * 16 + rsub + j;
                const size_t idx = (size_t)gm * H_ + gn;
                const float z = acc[mi][ni][j] + bv;
                if (MODE == 0) {
                    const float sp = (z > 15.f) ? z : log1pf(expf(z));
                    outf[idx] = 1.0f / (sp + 1e-6f);
                } else if (MODE == 1) {
                    const float r = 1.0f / (1.0f + expf(-z));
                    outb[idx] = f2bf(r * hidden[idx]);
                } else {
                    const float h = hidden[idx];
                    outf[idx] = h + (tanhf(z) - h) * invtau[idx];
                }
            }
        }
    }
}

extern "C" void kernel_launch(void* const* d_in, const int* in_sizes, int n_in,
                              void* d_out, int out_size, void* d_ws, size_t ws_size,
                              hipStream_t stream) {
    (void)in_sizes; (void)n_in; (void)out_size; (void)ws_size;

    const float* x     = (const float*)d_in[0];
    const float* hid   = (const float*)d_in[1];
    const float* W_tau = (const float*)d_in[2];
    const float* b_tau = (const float*)d_in[3];
    const float* W_r   = (const float*)d_in[4];
    const float* b_r   = (const float*)d_in[5];
    const float* W_h   = (const float*)d_in[6];
    const float* b_h   = (const float*)d_in[7];

    // workspace layout (~85 MB)
    unsigned short* xb    = (unsigned short*)d_ws;                 // B_*I_
    unsigned short* hb    = xb    + (size_t)B_ * I_;               // B_*H_
    unsigned short* gated = hb    + (size_t)B_ * H_;               // B_*H_
    unsigned short* wtb   = gated + (size_t)B_ * H_;               // H_*K_
    unsigned short* wrb   = wtb   + (size_t)H_ * K_;               // H_*K_
    unsigned short* whb   = wrb   + (size_t)H_ * K_;               // H_*K_
    float*          itau  = (float*)(whb + (size_t)H_ * K_);       // B_*H_ f32

    const int th = 256;
    const int nxi = B_ * I_ / 8, nh = B_ * H_ / 8, nw = H_ * K_ / 8;
    cvt_bf16_kernel<<<(nxi + th - 1) / th, th, 0, stream>>>(x,     xb,  nxi);
    cvt_bf16_kernel<<<(nh  + th - 1) / th, th, 0, stream>>>(hid,   hb,  nh);
    cvt_bf16_kernel<<<(nw  + th - 1) / th, th, 0, stream>>>(W_tau, wtb, nw);
    cvt_bf16_kernel<<<(nw  + th - 1) / th, th, 0, stream>>>(W_r,   wrb, nw);
    cvt_bf16_kernel<<<(nw  + th - 1) / th, th, 0, stream>>>(W_h,   whb, nw);

    dim3 grid(H_ / 128, B_ / 128);   // 8 x 64
    gemm_ltc<0><<<grid, 256, 0, stream>>>(xb, hb, wtb, b_tau, nullptr, nullptr, itau, nullptr);
    gemm_ltc<1><<<grid, 256, 0, stream>>>(xb, hb, wrb, b_r, hid, nullptr, nullptr, gated);
    gemm_ltc<2><<<grid, 256, 0, stream>>>(xb, gated, whb, b_h, hid, itau, (float*)d_out, nullptr);
}